// Round 2
// baseline (763.014 us; speedup 1.0000x reference)
//
#include <hip/hip_runtime.h>
#include <hip/hip_bf16.h>
#include <math.h>

// ---- Problem constants (match reference) ----
#define B_    128
#define L_    512
#define H_    128
#define NPT_  1023          // 2L-1
#define N_    (B_ * NPT_)   // 130944
#define NLEAF (B_ * L_)     // 65536
#define OUT_  128

// Fast device math (accuracy ~1e-6, far below 2% tolerance)
__device__ __forceinline__ float sigmoidf_(float x) {
    return 1.0f / (1.0f + __expf(-x));
}
__device__ __forceinline__ float tanhf_(float x) {
    // 1 - 2/(e^{2x}+1); stable at both extremes
    return 1.0f - 2.0f / (__expf(2.0f * x) + 1.0f);
}

// storage-type helpers (state arrays may be f32 or bf16 depending on ws_size)
__device__ __forceinline__ float ldv(float v)            { return v; }
__device__ __forceinline__ float ldv(__hip_bfloat16 v)   { return __bfloat162float(v); }
__device__ __forceinline__ void  stv(float* p, float v)          { *p = v; }
__device__ __forceinline__ void  stv(__hip_bfloat16* p, float v) { *p = __float2bfloat16(v); }

// =====================================================================
// Leaf kernel: 8 leaves/block. iou = emb[label] @ W_iou (+b_iou);
// c = sig(i)*tanh(u); h = sig(o)*tanh(c). Thread j owns h-dim j.
// =====================================================================
template <typename T>
__global__ __launch_bounds__(128)
void leaf_kernel(const int* __restrict__ label,
                 const float* __restrict__ emb,
                 const float* __restrict__ W_iou,
                 const float* __restrict__ b_iou,
                 T* __restrict__ h,
                 T* __restrict__ c) {
    __shared__ float e[8][H_];          // 4 KB
    const int tid  = threadIdx.x;
    const int row0 = blockIdx.x * 8;    // leaf linear index base

    // stage 8 embedding rows (gather via label); r == t, k == tid
    #pragma unroll
    for (int t = 0; t < 8; ++t) {
        int li  = row0 + t;             // leaf linear index
        int b   = li >> 9;              // / 512
        int pos = li & 511;
        int g   = b * NPT_ + pos;       // global node id of leaf
        e[t][tid] = emb[(size_t)label[g] * H_ + tid];
    }
    __syncthreads();

    const int j = tid;
    float acc[3][8];
    #pragma unroll
    for (int s = 0; s < 3; ++s)
        #pragma unroll
        for (int r = 0; r < 8; ++r) acc[s][r] = 0.0f;

    for (int k = 0; k < H_; ++k) {
        float w0 = W_iou[k * 384 + j];          // i
        float w1 = W_iou[k * 384 + 128 + j];    // o
        float w2 = W_iou[k * 384 + 256 + j];    // u
        #pragma unroll
        for (int r = 0; r < 8; ++r) {
            float ek = e[r][k];
            acc[0][r] += w0 * ek;
            acc[1][r] += w1 * ek;
            acc[2][r] += w2 * ek;
        }
    }

    float bi = b_iou[j];
    float bo = b_iou[128 + j];
    float bu = b_iou[256 + j];
    #pragma unroll
    for (int r = 0; r < 8; ++r) {
        int li  = row0 + r;
        int b   = li >> 9;
        int pos = li & 511;
        int g   = b * NPT_ + pos;
        float iv = sigmoidf_(acc[0][r] + bi);
        float ov = sigmoidf_(acc[1][r] + bo);
        float uv = tanhf_(acc[2][r] + bu);
        float cv = iv * uv;                 // c_in = 0 at leaves
        float hv = ov * tanhf_(cv);
        stv(&c[(size_t)g * H_ + j], cv);
        stv(&h[(size_t)g * H_ + j], hv);
    }
}

// =====================================================================
// Level kernel: 8 nodes/block. h_cat[256] = [h_left | h_right].
// Thread j owns cols {j, j+128, j+256} of U_iou (i,o,u) and
// {j, j+128} of U_f_w (fl,fr) -> full cell update in-thread.
// =====================================================================
template <typename T>
__global__ __launch_bounds__(128)
void level_kernel(const float* __restrict__ U_iou,
                  const float* __restrict__ U_f_w,
                  const float* __restrict__ b_iou,
                  const float* __restrict__ U_f_b,
                  T* __restrict__ h,
                  T* __restrict__ c,
                  int node_base, int child_base, int lc) {
    __shared__ float e[8][256];         // 8 KB
    const int tid  = threadIdx.x;
    const int row0 = blockIdx.x * 8;    // level-linear node index base
    const int mask = (1 << lc) - 1;

    // stage 8 h_cat rows: r = t>>1, k = (t&1)*128 + tid  (coalesced)
    #pragma unroll
    for (int t = 0; t < 16; ++t) {
        int r = t >> 1;
        int k = ((t & 1) << 7) + tid;
        int i   = row0 + r;
        int b   = i >> lc;
        int pos = i & mask;
        int gc  = b * NPT_ + child_base + 2 * pos + (k >> 7); // left/right child
        e[r][k] = ldv(h[(size_t)gc * H_ + (k & 127)]);
    }
    __syncthreads();

    const int j = tid;
    float acc[5][8];
    #pragma unroll
    for (int s = 0; s < 5; ++s)
        #pragma unroll
        for (int r = 0; r < 8; ++r) acc[s][r] = 0.0f;

    for (int k = 0; k < 256; ++k) {
        float w0 = U_iou[k * 384 + j];          // i
        float w1 = U_iou[k * 384 + 128 + j];    // o
        float w2 = U_iou[k * 384 + 256 + j];    // u
        float w3 = U_f_w[k * 256 + j];          // fl
        float w4 = U_f_w[k * 256 + 128 + j];    // fr
        #pragma unroll
        for (int r = 0; r < 8; ++r) {
            float ek = e[r][k];
            acc[0][r] += w0 * ek;
            acc[1][r] += w1 * ek;
            acc[2][r] += w2 * ek;
            acc[3][r] += w3 * ek;
            acc[4][r] += w4 * ek;
        }
    }

    float bi  = b_iou[j];
    float bo  = b_iou[128 + j];
    float bu  = b_iou[256 + j];
    float bfl = U_f_b[j];
    float bfr = U_f_b[128 + j];
    #pragma unroll
    for (int r = 0; r < 8; ++r) {
        int i   = row0 + r;
        int b   = i >> lc;
        int pos = i & mask;
        int g   = b * NPT_ + node_base + pos;
        int gl  = b * NPT_ + child_base + 2 * pos;
        float iv = sigmoidf_(acc[0][r] + bi);
        float ov = sigmoidf_(acc[1][r] + bo);
        float uv = tanhf_(acc[2][r] + bu);
        float fl = sigmoidf_(acc[3][r] + bfl);
        float fr = sigmoidf_(acc[4][r] + bfr);
        float cv = iv * uv + fl * ldv(c[(size_t)gl * H_ + j])
                           + fr * ldv(c[(size_t)(gl + 1) * H_ + j]);
        float hv = ov * tanhf_(cv);
        stv(&c[(size_t)g * H_ + j], cv);
        stv(&h[(size_t)g * H_ + j], hv);
    }
}

// =====================================================================
// Root kernel: one block per tree. logits = h_root @ W_out + b_out,
// then log_softmax over OUT=128.
// =====================================================================
template <typename T>
__global__ __launch_bounds__(128)
void root_kernel(const T* __restrict__ h,
                 const float* __restrict__ W_out,
                 const float* __restrict__ b_out,
                 float* __restrict__ out) {
    __shared__ float e[H_];
    __shared__ float red[128];
    const int j = threadIdx.x;
    const int b = blockIdx.x;
    const int g = b * NPT_ + (NPT_ - 1);    // root node

    e[j] = ldv(h[(size_t)g * H_ + j]);
    __syncthreads();

    float acc = b_out[j];
    for (int k = 0; k < H_; ++k)
        acc += e[k] * W_out[k * OUT_ + j];

    // max-reduce
    red[j] = acc; __syncthreads();
    #pragma unroll
    for (int s = 64; s > 0; s >>= 1) {
        if (j < s) red[j] = fmaxf(red[j], red[j + s]);
        __syncthreads();
    }
    float mx = red[0]; __syncthreads();

    // sum(exp)
    red[j] = expf(acc - mx); __syncthreads();
    #pragma unroll
    for (int s = 64; s > 0; s >>= 1) {
        if (j < s) red[j] += red[j + s];
        __syncthreads();
    }
    float lse = logf(red[0]);

    out[b * OUT_ + j] = acc - mx - lse;
}

// =====================================================================
template <typename T>
static void run_all(const void* const* d_in, float* out, void* d_ws, hipStream_t stream) {
    const int*   label = (const int*)d_in[0];
    const float* emb   = (const float*)d_in[1];
    const float* W_iou = (const float*)d_in[2];
    const float* U_iou = (const float*)d_in[3];
    const float* b_iou = (const float*)d_in[4];
    const float* U_f_w = (const float*)d_in[5];
    const float* U_f_b = (const float*)d_in[6];
    const float* W_out = (const float*)d_in[7];
    const float* b_out = (const float*)d_in[8];

    T* c = (T*)d_ws;
    T* h = c + (size_t)N_ * H_;

    leaf_kernel<T><<<NLEAF / 8, 128, 0, stream>>>(label, emb, W_iou, b_iou, h, c);

    // static level schedule
    int child = 0, node = 512, cnt = 256, lc = 8;
    for (int lvl = 0; lvl < 9; ++lvl) {
        level_kernel<T><<<(B_ * cnt) / 8, 128, 0, stream>>>(
            U_iou, U_f_w, b_iou, U_f_b, h, c, node, child, lc);
        child = node; node += cnt; cnt >>= 1; --lc;
    }

    root_kernel<T><<<B_, 128, 0, stream>>>(h, W_out, b_out, out);
}

extern "C" void kernel_launch(void* const* d_in, const int* in_sizes, int n_in,
                              void* d_out, int out_size, void* d_ws, size_t ws_size,
                              hipStream_t stream) {
    const size_t need_f32 = (size_t)N_ * H_ * sizeof(float) * 2;   // c + h, ~134 MB
    if (ws_size >= need_f32) {
        run_all<float>((const void* const*)d_in, (float*)d_out, d_ws, stream);
    } else {
        run_all<__hip_bfloat16>((const void* const*)d_in, (float*)d_out, d_ws, stream);
    }
}

// Round 3
// 354.334 us; speedup vs baseline: 2.1534x; 2.1534x over previous
//
#include <hip/hip_runtime.h>
#include <math.h>

// ---- Problem constants ----
#define B_    128
#define L_    512
#define H_    128
#define NPT_  1023
#define N_    (B_ * NPT_)     // 130944
#define NLEAF (B_ * L_)       // 65536
#define OUT_  128

typedef unsigned short ushort_t;
typedef __attribute__((ext_vector_type(8))) __bf16 bf16x8;
typedef __attribute__((ext_vector_type(4))) float f32x4;

__device__ __forceinline__ float sigmoidf_(float x) {
    return 1.0f / (1.0f + __expf(-x));
}
__device__ __forceinline__ float tanhf_(float x) {
    return 1.0f - 2.0f / (__expf(2.0f * x) + 1.0f);
}
// bf16 <-> f32 on raw bits (RNE), independent of header internals
__device__ __forceinline__ ushort_t f2bf(float f) {
    unsigned u = __float_as_uint(f);
    return (ushort_t)((u + 0x7fffu + ((u >> 16) & 1u)) >> 16);
}
__device__ __forceinline__ float bf2f(ushort_t s) {
    return __uint_as_float(((unsigned)s) << 16);
}

// =====================================================================
// Prep: cast weights to bf16, transposed so MFMA B-fragments are
// contiguous. U_catT[n][k]: n<384 -> U_iou[k][n]; n>=384 -> U_f_w[k][n-384].
// W_iouT[n][k] = W_iou[k][n].
// =====================================================================
__global__ __launch_bounds__(256)
void prep_kernel(const float* __restrict__ W_iou,
                 const float* __restrict__ U_iou,
                 const float* __restrict__ U_f_w,
                 ushort_t* __restrict__ W_iouT,     // [384][128]
                 ushort_t* __restrict__ U_catT) {   // [640][256]
    int idx = blockIdx.x * 256 + threadIdx.x;
    if (idx < 640 * 256) {
        int n = idx >> 8, k = idx & 255;
        float v = (n < 384) ? U_iou[k * 384 + n] : U_f_w[k * 256 + (n - 384)];
        U_catT[idx] = f2bf(v);
    }
    if (idx < 384 * 128) {
        int n = idx >> 7, k = idx & 127;
        W_iouT[idx] = f2bf(W_iou[k * 384 + n]);
    }
}

// =====================================================================
// Leaf: MFMA GEMM [64 leaves/block] x [128 -> 384] + cell epilogue.
// 2 waves/block, each wave: M=32 (2 subtiles of 16), all 8 gate-groups.
// Gate-group g covers output dims j in [16g,16g+16): tiles {g, g+8, g+16}
// = (i, o, u) — all three land in the same lane => lane-local epilogue.
// =====================================================================
__global__ __launch_bounds__(128)
void leaf_mfma(const int* __restrict__ label,
               const float* __restrict__ emb,
               const ushort_t* __restrict__ WT,     // [384][128] bf16
               const float* __restrict__ b_iou,
               ushort_t* __restrict__ h,
               float* __restrict__ c) {
    const int lane = threadIdx.x & 63;
    const int wave = threadIdx.x >> 6;
    const int li   = lane & 15;
    const int q8   = (lane >> 4) << 3;
    const int i0   = blockIdx.x * 64 + wave * 32;

    // A fragments: emb[label] rows, f32 -> bf16
    bf16x8 a[2][4];
    #pragma unroll
    for (int sub = 0; sub < 2; ++sub) {
        int i = i0 + sub * 16 + li;
        int b = i >> 9, pos = i & 511;
        const float* er = emb + (size_t)label[b * NPT_ + pos] * H_;
        #pragma unroll
        for (int kt = 0; kt < 4; ++kt) {
            int kg = kt * 32 + q8;
            f32x4 f0 = *(const f32x4*)(er + kg);
            f32x4 f1 = *(const f32x4*)(er + kg + 4);
            union { bf16x8 v; ushort_t e[8]; } u;
            u.e[0] = f2bf(f0[0]); u.e[1] = f2bf(f0[1]);
            u.e[2] = f2bf(f0[2]); u.e[3] = f2bf(f0[3]);
            u.e[4] = f2bf(f1[0]); u.e[5] = f2bf(f1[1]);
            u.e[6] = f2bf(f1[2]); u.e[7] = f2bf(f1[3]);
            a[sub][kt] = u.v;
        }
    }

    for (int g = 0; g < 8; ++g) {
        const int j = g * 16 + li;
        const ushort_t* bp[3];
        #pragma unroll
        for (int t = 0; t < 3; ++t)
            bp[t] = WT + (size_t)(16 * (g + 8 * t) + li) * 128 + q8;

        f32x4 acc[2][3];
        #pragma unroll
        for (int s = 0; s < 2; ++s)
            #pragma unroll
            for (int t = 0; t < 3; ++t) acc[s][t] = (f32x4){0.f, 0.f, 0.f, 0.f};

        #pragma unroll
        for (int kt = 0; kt < 4; ++kt) {
            #pragma unroll
            for (int t = 0; t < 3; ++t) {
                bf16x8 bf = *(const bf16x8*)(bp[t] + kt * 32);
                acc[0][t] = __builtin_amdgcn_mfma_f32_16x16x32_bf16(a[0][kt], bf, acc[0][t], 0, 0, 0);
                acc[1][t] = __builtin_amdgcn_mfma_f32_16x16x32_bf16(a[1][kt], bf, acc[1][t], 0, 0, 0);
            }
        }

        const float bi = b_iou[j], bo = b_iou[128 + j], bu = b_iou[256 + j];
        #pragma unroll
        for (int sub = 0; sub < 2; ++sub) {
            #pragma unroll
            for (int r = 0; r < 4; ++r) {
                int m  = i0 + sub * 16 + q8 / 2 + r;   // row = 4*quad + reg
                int b  = m >> 9, pos = m & 511;
                size_t gn = (size_t)(b * NPT_ + pos) * H_ + j;
                float iv = sigmoidf_(acc[sub][0][r] + bi);
                float ov = sigmoidf_(acc[sub][1][r] + bo);
                float uv = tanhf_(acc[sub][2][r] + bu);
                float cv = iv * uv;                    // c_in = 0 at leaves
                float hv = ov * tanhf_(cv);
                c[gn] = cv;
                h[gn] = f2bf(hv);
            }
        }
    }
}

// =====================================================================
// Level: MFMA GEMM [nodes x 256] x [256 -> 640] + cell epilogue.
// Gate-group g: tiles {g, g+8, g+16, g+24, g+32} = (i,o,u,fl,fr),
// lane-local epilogue with c-children gathered from f32 state.
// blockIdx.y splits gate-groups for small levels.
// =====================================================================
__global__ __launch_bounds__(128)
void level_mfma(const ushort_t* __restrict__ Ucat,   // [640][256] bf16
                const float* __restrict__ b_iou,
                const float* __restrict__ U_f_b,
                ushort_t* __restrict__ h,
                float* __restrict__ c,
                int node_base, int child_base, int lc, int gpb) {
    const int lane = threadIdx.x & 63;
    const int wave = threadIdx.x >> 6;
    const int li   = lane & 15;
    const int q8   = (lane >> 4) << 3;
    const int mask = (1 << lc) - 1;
    const int i0   = blockIdx.x * 64 + wave * 32;

    // A fragments: h_cat rows gathered from children's bf16 h-state.
    // k in [0,128) = left child, [128,256) = right child.
    bf16x8 a[2][8];
    #pragma unroll
    for (int sub = 0; sub < 2; ++sub) {
        int i  = i0 + sub * 16 + li;
        int b  = i >> lc, pos = i & mask;
        int gl = b * NPT_ + child_base + 2 * pos;
        #pragma unroll
        for (int kt = 0; kt < 8; ++kt) {
            int kg = kt * 32 + q8;
            int gc = gl + (kg >> 7);
            a[sub][kt] = *(const bf16x8*)(h + (size_t)gc * H_ + (kg & 127));
        }
    }

    const int g0 = blockIdx.y * gpb;
    for (int gi = 0; gi < gpb; ++gi) {
        const int gg = g0 + gi;
        const int j  = gg * 16 + li;
        const ushort_t* bp[5];
        #pragma unroll
        for (int t = 0; t < 5; ++t)
            bp[t] = Ucat + (size_t)(16 * (gg + 8 * t) + li) * 256 + q8;

        f32x4 acc[2][5];
        #pragma unroll
        for (int s = 0; s < 2; ++s)
            #pragma unroll
            for (int t = 0; t < 5; ++t) acc[s][t] = (f32x4){0.f, 0.f, 0.f, 0.f};

        #pragma unroll
        for (int kt = 0; kt < 8; ++kt) {
            #pragma unroll
            for (int t = 0; t < 5; ++t) {
                bf16x8 bf = *(const bf16x8*)(bp[t] + kt * 32);
                acc[0][t] = __builtin_amdgcn_mfma_f32_16x16x32_bf16(a[0][kt], bf, acc[0][t], 0, 0, 0);
                acc[1][t] = __builtin_amdgcn_mfma_f32_16x16x32_bf16(a[1][kt], bf, acc[1][t], 0, 0, 0);
            }
        }

        const float bi  = b_iou[j], bo = b_iou[128 + j], bu = b_iou[256 + j];
        const float bfl = U_f_b[j], bfr = U_f_b[128 + j];
        #pragma unroll
        for (int sub = 0; sub < 2; ++sub) {
            #pragma unroll
            for (int r = 0; r < 4; ++r) {
                int m   = i0 + sub * 16 + q8 / 2 + r;  // row = 4*quad + reg
                int b   = m >> lc, pos = m & mask;
                int gn  = b * NPT_ + node_base + pos;
                int gl  = b * NPT_ + child_base + 2 * pos;
                float iv = sigmoidf_(acc[sub][0][r] + bi);
                float ov = sigmoidf_(acc[sub][1][r] + bo);
                float uv = tanhf_(acc[sub][2][r] + bu);
                float fl = sigmoidf_(acc[sub][3][r] + bfl);
                float fr = sigmoidf_(acc[sub][4][r] + bfr);
                float cv = iv * uv + fl * c[(size_t)gl * H_ + j]
                                   + fr * c[(size_t)(gl + 1) * H_ + j];
                float hv = ov * tanhf_(cv);
                c[(size_t)gn * H_ + j] = cv;
                h[(size_t)gn * H_ + j] = f2bf(hv);
            }
        }
    }
}

// =====================================================================
// Root: logits = h_root @ W_out + b_out, log_softmax. Tiny; f32 VALU.
// =====================================================================
__global__ __launch_bounds__(128)
void root_kernel(const ushort_t* __restrict__ h,
                 const float* __restrict__ W_out,
                 const float* __restrict__ b_out,
                 float* __restrict__ out) {
    __shared__ float e[H_];
    __shared__ float red[128];
    const int j = threadIdx.x;
    const int b = blockIdx.x;
    const size_t g = (size_t)(b * NPT_ + (NPT_ - 1)) * H_;

    e[j] = bf2f(h[g + j]);
    __syncthreads();

    float acc = b_out[j];
    for (int k = 0; k < H_; ++k)
        acc += e[k] * W_out[k * OUT_ + j];

    red[j] = acc; __syncthreads();
    #pragma unroll
    for (int s = 64; s > 0; s >>= 1) {
        if (j < s) red[j] = fmaxf(red[j], red[j + s]);
        __syncthreads();
    }
    float mx = red[0]; __syncthreads();

    red[j] = expf(acc - mx); __syncthreads();
    #pragma unroll
    for (int s = 64; s > 0; s >>= 1) {
        if (j < s) red[j] += red[j + s];
        __syncthreads();
    }
    float lse = logf(red[0]);

    out[b * OUT_ + j] = acc - mx - lse;
}

// =====================================================================
extern "C" void kernel_launch(void* const* d_in, const int* in_sizes, int n_in,
                              void* d_out, int out_size, void* d_ws, size_t ws_size,
                              hipStream_t stream) {
    const int*   label = (const int*)d_in[0];
    const float* emb   = (const float*)d_in[1];
    const float* W_iou = (const float*)d_in[2];
    const float* U_iou = (const float*)d_in[3];
    const float* b_iou = (const float*)d_in[4];
    const float* U_f_w = (const float*)d_in[5];
    const float* U_f_b = (const float*)d_in[6];
    const float* W_out = (const float*)d_in[7];
    const float* b_out = (const float*)d_in[8];

    // ws layout: c f32 (67 MB) | h bf16 (33.5 MB) | U_catT | W_iouT  (~101 MB)
    float*    c    = (float*)d_ws;
    ushort_t* h    = (ushort_t*)(c + (size_t)N_ * H_);
    ushort_t* Ucat = h + (size_t)N_ * H_;
    ushort_t* WT   = Ucat + 640 * 256;

    prep_kernel<<<640, 256, 0, stream>>>(W_iou, U_iou, U_f_w, WT, Ucat);

    leaf_mfma<<<NLEAF / 64, 128, 0, stream>>>(label, emb, WT, b_iou, h, c);

    int child = 0, node = 512, cnt = 256, lc = 8;
    for (int lvl = 0; lvl < 9; ++lvl) {
        int mb = (B_ * cnt) / 64;
        int gs = 1;
        while (mb * gs < 256 && gs < 8) gs <<= 1;   // gate-group split for tail levels
        level_mfma<<<dim3(mb, gs), 128, 0, stream>>>(
            Ucat, b_iou, U_f_b, h, c, node, child, lc, 8 / gs);
        child = node; node += cnt; cnt >>= 1; --lc;
    }

    root_kernel<<<B_, 128, 0, stream>>>(h, W_out, b_out, (float*)d_out);
}